// Round 1
// baseline (200.990 us; speedup 1.0000x reference)
//
#include <hip/hip_runtime.h>

// GAT: B=256, N=64, K=12, D=128
// Algebraic reduction: q/k projections fold into effective vectors
//   wq_eff = Wq @ wa_q, wk_eff = Wk @ wa_k
// and V-projection commutes with the attention average:
//   out = (sum_j attn_j nh_j) @ Wv + bv * (sum_j attn_j)
//
// R2: restructure for latency, not bandwidth (we were 10x off the 19us
// HBM roofline at 187.5us):
//  - float4 loads: one wave load = TWO neighbor vectors (lanes 0-31 get
//    vector 2i, lanes 32-63 vector 2i+1). 7 load instrs/pair vs 14.
//  - reduce-scatter (3 stages + 2 finish) over the 8 per-half partial dots
//    instead of 14-value full butterfly: ~25 shuffles/pair vs 84; 2 exps
//    per lane vs 13.
//  - grid 512 -> 2048 blocks (8 pairs/block, wave does 2 pairs): 4x the
//    blocks/CU to hide HBM latency; launch_bounds caps VGPR at 128.

#define B_  256
#define N_  64
#define K_  12
#define D_  128
#define BN  (B_ * N_)          // 16384 (b,n) pairs
#define ROWS 8                 // pairs per block
#define HB_STRIDE 132

// ws float layout: [0..127] wq_eff | [128..255] wk_eff | [256] cq | [257] ckb
// ---------------------------------------------------------------------------
__global__ void prep_kernel(const float* __restrict__ Wq, const float* __restrict__ bq,
                            const float* __restrict__ Wk, const float* __restrict__ bk,
                            const float* __restrict__ wa_q, const float* __restrict__ wa_k,
                            float* __restrict__ ws) {
    int g = blockIdx.x;
    int l = threadIdx.x;            // 0..63, lane owns elements 2l, 2l+1
    const float* row;
    const float* wa;
    float* outp;
    if (g < 128)      { row = Wq + g * D_;         wa = wa_q; outp = ws + g; }
    else if (g < 256) { row = Wk + (g - 128) * D_; wa = wa_k; outp = ws + 128 + (g - 128); }
    else if (g == 256){ row = bq;                  wa = wa_q; outp = ws + 256; }
    else              { row = bk;                  wa = wa_k; outp = ws + 257; }

    float2 r = ((const float2*)row)[l];
    float2 w = ((const float2*)wa)[l];
    float p = r.x * w.x + r.y * w.y;
    #pragma unroll
    for (int m = 1; m < 64; m <<= 1) p += __shfl_xor(p, m, 64);
    if (l == 0) *outp = p;
}

// ---------------------------------------------------------------------------
// Fused kernel. grid = BN/8 = 2048 blocks x 256 threads. Block owns 8 pairs.
// Phase A: wave w handles pairs w*2, w*2+1. Lane l: half h=l>>5, li=l&31
//          owns features 4li..4li+3. Neighbor vectors are split across
//          halves: half h holds slots {1+2i+h}. 8 partial dots per lane are
//          reduce-scattered so lane (l&7) ends with one full dot sum.
// Phase B: out[8x128] = hb @ Wv + bv*scale. Thread (rg=t>>5, cg=t&31) does
//          row rg, cols 4cg..4cg+3. hb reads are 2-addr broadcast: free.
__global__ void __launch_bounds__(256, 4)
fused_kernel(const float* __restrict__ nodes, const float* __restrict__ neigh,
             const float* __restrict__ mask, const float* __restrict__ ba_p,
             const float* __restrict__ ws, const float* __restrict__ Wv,
             const float* __restrict__ bv, float* __restrict__ out) {
    __shared__ float hb[ROWS * HB_STRIDE];
    __shared__ float scL[ROWS];

    const int t    = threadIdx.x;
    const int wave = t >> 6;
    const int l    = t & 63;
    const int li   = l & 31;        // feature-group index (features 4li..4li+3)
    const int h    = l >> 5;        // which half-wave (vector parity)
    const int j8   = l & 7;         // value index after reduce-scatter

    const float cq  = ws[256];
    const float ckb = ws[257];
    const float ba  = ba_p[0];
    const float cst = cq + ckb + ba;
    const float4 wqe4 = ((const float4*)ws)[li];          // wq_eff[4li..]
    const float4 wke4 = ((const float4*)(ws + 128))[li];  // wk_eff[4li..]

    // ---- Phase A: attention + pooling for this wave's 2 pairs ----
    for (int p = 0; p < 2; ++p) {
        const int lrow = wave * 2 + p;                 // 0..7 local row
        const int idx  = blockIdx.x * ROWS + lrow;     // (b,n) flat index

        // node features 4li..4li+3 (both halves load the same 512B)
        const float4 nv = ((const float4*)(nodes + (size_t)idx * D_))[li];
        // neighbors: load i covers vectors 2i (h=0) and 2i+1 (h=1)
        const float4* gp4 = (const float4*)(neigh + (size_t)idx * (K_ * D_));
        float4 x[6];
        #pragma unroll
        for (int i = 0; i < 6; ++i) x[i] = gp4[i * 64 + l];
        // my slot after RS is neighbor (2*j8 + h), valid for j8 < 6
        const float mval = (j8 < 6) ? mask[(size_t)idx * K_ + 2 * j8 + h] : 0.0f;

        // 8 per-lane partial dots (each half covers all 128 features)
        float v[8];
        v[7] = nv.x*wqe4.x + nv.y*wqe4.y + nv.z*wqe4.z + nv.w*wqe4.w;   // pq
        v[6] = nv.x*wke4.x + nv.y*wke4.y + nv.z*wke4.z + nv.w*wke4.w;   // pk node
        #pragma unroll
        for (int i = 0; i < 6; ++i)
            v[i] = x[i].x*wke4.x + x[i].y*wke4.y + x[i].z*wke4.z + x[i].w*wke4.w;

        // reduce-scatter over value bits (masks 1,2,4): lane ends holding
        // value (l&7) summed over its 8-lane coset, then 2 finishing
        // butterflies complete the 32-lane sum. 9 shuffles vs 40.
        float a0, a1, a2, a3;
        {
            const bool hi = (l & 1);
            float g0 = hi ? v[0] : v[1];
            float g1 = hi ? v[2] : v[3];
            float g2 = hi ? v[4] : v[5];
            float g3 = hi ? v[6] : v[7];
            g0 = __shfl_xor(g0, 1, 64);
            g1 = __shfl_xor(g1, 1, 64);
            g2 = __shfl_xor(g2, 1, 64);
            g3 = __shfl_xor(g3, 1, 64);
            a0 = (hi ? v[1] : v[0]) + g0;
            a1 = (hi ? v[3] : v[2]) + g1;
            a2 = (hi ? v[5] : v[4]) + g2;
            a3 = (hi ? v[7] : v[6]) + g3;
        }
        float b0, b1;
        {
            const bool hi = (l & 2);
            float g0 = hi ? a0 : a1;
            float g1 = hi ? a2 : a3;
            g0 = __shfl_xor(g0, 2, 64);
            g1 = __shfl_xor(g1, 2, 64);
            b0 = (hi ? a1 : a0) + g0;
            b1 = (hi ? a3 : a2) + g1;
        }
        float c;
        {
            const bool hi = (l & 4);
            float g = hi ? b0 : b1;
            g = __shfl_xor(g, 4, 64);
            c = (hi ? b1 : b0) + g;
        }
        c += __shfl_xor(c, 8, 64);
        c += __shfl_xor(c, 16, 64);
        // c = full dot of value j8: j8<6 -> slot 1+2*j8+h; 6 -> node k-dot; 7 -> q-dot

        const float pq  = __shfl(c, 7, 8);     // replicated in every 8-group
        const float pkn = __shfl(c, 6, 8);
        const float base = pq + cst;

        float s0 = base + pkn;                          // node slot score
        s0 = (s0 >= 0.0f) ? s0 : 0.2f * s0;
        const float e0 = __expf(s0);

        float sj = base + c;                            // my slot's score
        sj = (sj >= 0.0f) ? sj : 0.2f * sj;
        const float ej = (j8 < 6) ? __expf(sj) * mval : 0.0f;

        // denominator: sum my half's 6 neighbor e's, add other half, add node
        float Sn = ej;
        Sn += __shfl_xor(Sn, 1, 64);
        Sn += __shfl_xor(Sn, 2, 64);
        Sn += __shfl_xor(Sn, 4, 64);
        Sn += __shfl_xor(Sn, 32, 64);
        const float S   = e0 + Sn;
        const float inv = 1.0f / (S + 1e-16f);
        const float aj  = ej * inv;                     // attn of my slot

        // pooling: partial over my half's 7 slots (node counted once, h==0)
        const float an = (h == 0) ? e0 * inv : 0.0f;
        float4 acc;
        acc.x = an * nv.x; acc.y = an * nv.y; acc.z = an * nv.z; acc.w = an * nv.w;
        #pragma unroll
        for (int i = 0; i < 6; ++i) {
            const float ai = __shfl(aj, i, 8);          // attn of slot 1+2i+h
            acc.x += ai * x[i].x;
            acc.y += ai * x[i].y;
            acc.z += ai * x[i].z;
            acc.w += ai * x[i].w;
        }
        acc.x += __shfl_xor(acc.x, 32, 64);             // combine halves
        acc.y += __shfl_xor(acc.y, 32, 64);
        acc.z += __shfl_xor(acc.z, 32, 64);
        acc.w += __shfl_xor(acc.w, 32, 64);

        if (h == 0) {
            *(float4*)(hb + lrow * HB_STRIDE + 4 * li) = acc;
            if (li == 0) scL[lrow] = S * inv;           // sum of attn weights
        }
    }
    __syncthreads();

    // ---- Phase B: out[8x128] = hb @ Wv + bv * scale ----
    const int rg = t >> 5;                        // row 0..7
    const int cg = t & 31;                        // cols 4cg..4cg+3
    const float4* wv4 = (const float4*)Wv;        // [k][32] of float4
    const float* hrow = hb + rg * HB_STRIDE;

    float4 vacc = make_float4(0.0f, 0.0f, 0.0f, 0.0f);
    #pragma unroll 8
    for (int k = 0; k < D_; ++k) {
        const float a  = hrow[k];                 // 2 addrs/wave: broadcast, free
        const float4 w = wv4[k * 32 + cg];
        vacc.x += a * w.x;
        vacc.y += a * w.y;
        vacc.z += a * w.z;
        vacc.w += a * w.w;
    }

    const float4 bvv = ((const float4*)bv)[cg];
    const float  s   = scL[rg];
    float4 o;
    o.x = vacc.x + bvv.x * s;
    o.y = vacc.y + bvv.y * s;
    o.z = vacc.z + bvv.z * s;
    o.w = vacc.w + bvv.w * s;
    *(float4*)(out + (size_t)(blockIdx.x * ROWS + rg) * D_ + cg * 4) = o;
}

// ---------------------------------------------------------------------------
extern "C" void kernel_launch(void* const* d_in, const int* in_sizes, int n_in,
                              void* d_out, int out_size, void* d_ws, size_t ws_size,
                              hipStream_t stream) {
    const float* nodes = (const float*)d_in[0];
    const float* neigh = (const float*)d_in[1];
    const float* mask  = (const float*)d_in[2];
    const float* Wq    = (const float*)d_in[3];
    const float* bq    = (const float*)d_in[4];
    const float* Wk    = (const float*)d_in[5];
    const float* bk    = (const float*)d_in[6];
    const float* Wv    = (const float*)d_in[7];
    const float* bv    = (const float*)d_in[8];
    const float* wa_q  = (const float*)d_in[9];
    const float* wa_k  = (const float*)d_in[10];
    const float* ba    = (const float*)d_in[11];
    float* out = (float*)d_out;
    float* ws  = (float*)d_ws;

    prep_kernel<<<258, 64, 0, stream>>>(Wq, bq, Wk, bk, wa_q, wa_k, ws);
    fused_kernel<<<BN / ROWS, 256, 0, stream>>>(nodes, neigh, mask, ba, ws, Wv, bv, out);
}

// Round 2
// 199.116 us; speedup vs baseline: 1.0094x; 1.0094x over previous
//
#include <hip/hip_runtime.h>

// GAT: B=256, N=64, K=12, D=128
// Algebra: wq_eff = Wq @ wa_q, wk_eff = Wk @ wa_k; V-projection commutes
// with the attention average: out = h_bar @ Wv + bv * (sum attn).
//
// R3: latency attack (R2 was 88% stalled, VGPR=36 -> idle register file):
//  - prefetch BOTH pairs' neighbors/node/mask before any compute (14 global
//    loads in flight; pair1's HBM wait hides under pair0's chain)
//  - interleave the two pairs' shuffle chains stage-by-stage (independent
//    DS ops pipeline 2-deep; lgkmcnt completes in-order)
//  - Sn reduction deleted: pool with raw e-weights, accumulate Se from the
//    same broadcasts, normalize once after the cross-half combine
//    (dependent DS stages per pair: 12 -> 8)
//  - Phase B unroll 16 (Phase A regs dead there; more Wv loads in flight)

#define B_  256
#define N_  64
#define K_  12
#define D_  128
#define BN  (B_ * N_)          // 16384 (b,n) pairs
#define ROWS 8                 // pairs per block
#define HB_STRIDE 132

// ws float layout: [0..127] wq_eff | [128..255] wk_eff | [256] cq | [257] ckb
// ---------------------------------------------------------------------------
__global__ void prep_kernel(const float* __restrict__ Wq, const float* __restrict__ bq,
                            const float* __restrict__ Wk, const float* __restrict__ bk,
                            const float* __restrict__ wa_q, const float* __restrict__ wa_k,
                            float* __restrict__ ws) {
    int g = blockIdx.x;
    int l = threadIdx.x;            // 0..63, lane owns elements 2l, 2l+1
    const float* row;
    const float* wa;
    float* outp;
    if (g < 128)      { row = Wq + g * D_;         wa = wa_q; outp = ws + g; }
    else if (g < 256) { row = Wk + (g - 128) * D_; wa = wa_k; outp = ws + 128 + (g - 128); }
    else if (g == 256){ row = bq;                  wa = wa_q; outp = ws + 256; }
    else              { row = bk;                  wa = wa_k; outp = ws + 257; }

    float2 r = ((const float2*)row)[l];
    float2 w = ((const float2*)wa)[l];
    float p = r.x * w.x + r.y * w.y;
    #pragma unroll
    for (int m = 1; m < 64; m <<= 1) p += __shfl_xor(p, m, 64);
    if (l == 0) *outp = p;
}

// ---------------------------------------------------------------------------
// grid = BN/8 = 2048 blocks x 256 threads. Block owns 8 pairs; wave owns 2.
// Lane l: half h=l>>5 covers neighbor slots {1+2i+h}; li=l&31 owns features
// 4li..4li+3. After 3 RS + 2 finish stages lane (l&7) holds one full dot.
__global__ void __launch_bounds__(256)
fused_kernel(const float* __restrict__ nodes, const float* __restrict__ neigh,
             const float* __restrict__ mask, const float* __restrict__ ba_p,
             const float* __restrict__ ws, const float* __restrict__ Wv,
             const float* __restrict__ bv, float* __restrict__ out) {
    __shared__ float hb[ROWS * HB_STRIDE];
    __shared__ float scL[ROWS];

    const int t    = threadIdx.x;
    const int wave = t >> 6;
    const int l    = t & 63;
    const int li   = l & 31;
    const int h    = l >> 5;
    const int j8   = l & 7;

    const float cq  = ws[256];
    const float ckb = ws[257];
    const float ba  = ba_p[0];
    const float cst = cq + ckb + ba;
    const float4 wqe4 = ((const float4*)ws)[li];          // wq_eff[4li..]
    const float4 wke4 = ((const float4*)(ws + 128))[li];  // wk_eff[4li..]

    const int idx0 = blockIdx.x * ROWS + wave * 2;

    // ---- prefetch BOTH pairs: 2 node + 12 neighbor + 2 mask loads ----
    float4 nv[2];
    float4 x[2][6];
    float  mv[2];
    #pragma unroll
    for (int p = 0; p < 2; ++p) {
        const int idx = idx0 + p;
        nv[p] = ((const float4*)(nodes + (size_t)idx * D_))[li];
        const float4* gp4 = (const float4*)(neigh + (size_t)idx * (K_ * D_));
        #pragma unroll
        for (int i = 0; i < 6; ++i) x[p][i] = gp4[i * 64 + l];
        mv[p] = (j8 < 6) ? mask[(size_t)idx * K_ + 2 * j8 + h] : 0.0f;
    }

    // ---- per-lane partial dots (8 values per pair) ----
    float v[2][8];
    #pragma unroll
    for (int p = 0; p < 2; ++p) {
        v[p][7] = nv[p].x*wqe4.x + nv[p].y*wqe4.y + nv[p].z*wqe4.z + nv[p].w*wqe4.w;
        v[p][6] = nv[p].x*wke4.x + nv[p].y*wke4.y + nv[p].z*wke4.z + nv[p].w*wke4.w;
        #pragma unroll
        for (int i = 0; i < 6; ++i)
            v[p][i] = x[p][i].x*wke4.x + x[p][i].y*wke4.y
                    + x[p][i].z*wke4.z + x[p][i].w*wke4.w;
    }

    // ---- reduce-scatter, both pairs interleaved per stage ----
    float A[2][4];
    {
        const bool hi = (l & 1);
        #pragma unroll
        for (int p = 0; p < 2; ++p) {
            float g0 = hi ? v[p][0] : v[p][1];
            float g1 = hi ? v[p][2] : v[p][3];
            float g2 = hi ? v[p][4] : v[p][5];
            float g3 = hi ? v[p][6] : v[p][7];
            g0 = __shfl_xor(g0, 1, 64);
            g1 = __shfl_xor(g1, 1, 64);
            g2 = __shfl_xor(g2, 1, 64);
            g3 = __shfl_xor(g3, 1, 64);
            A[p][0] = (hi ? v[p][1] : v[p][0]) + g0;
            A[p][1] = (hi ? v[p][3] : v[p][2]) + g1;
            A[p][2] = (hi ? v[p][5] : v[p][4]) + g2;
            A[p][3] = (hi ? v[p][7] : v[p][6]) + g3;
        }
    }
    float Bs[2][2];
    {
        const bool hi = (l & 2);
        #pragma unroll
        for (int p = 0; p < 2; ++p) {
            float g0 = hi ? A[p][0] : A[p][1];
            float g1 = hi ? A[p][2] : A[p][3];
            g0 = __shfl_xor(g0, 2, 64);
            g1 = __shfl_xor(g1, 2, 64);
            Bs[p][0] = (hi ? A[p][1] : A[p][0]) + g0;
            Bs[p][1] = (hi ? A[p][3] : A[p][2]) + g1;
        }
    }
    float c[2];
    {
        const bool hi = (l & 4);
        #pragma unroll
        for (int p = 0; p < 2; ++p) {
            float g = hi ? Bs[p][0] : Bs[p][1];
            g = __shfl_xor(g, 4, 64);
            c[p] = (hi ? Bs[p][1] : Bs[p][0]) + g;
        }
    }
    #pragma unroll
    for (int p = 0; p < 2; ++p) c[p] += __shfl_xor(c[p], 8, 64);
    #pragma unroll
    for (int p = 0; p < 2; ++p) c[p] += __shfl_xor(c[p], 16, 64);
    // c[p] = full dot of value j8: j8<6 -> slot 1+2*j8+h; 6 -> node-k; 7 -> q

    float pq[2], pkn[2];
    #pragma unroll
    for (int p = 0; p < 2; ++p) {
        pq[p]  = __shfl(c[p], 7, 8);       // replicated within each 8-group
        pkn[p] = __shfl(c[p], 6, 8);
    }

    float e0[2], ej[2];
    #pragma unroll
    for (int p = 0; p < 2; ++p) {
        const float base = pq[p] + cst;
        float s0 = base + pkn[p];
        s0 = (s0 >= 0.0f) ? s0 : 0.2f * s0;          // LeakyReLU(0.2)
        e0[p] = __expf(s0);
        float sj = base + c[p];
        sj = (sj >= 0.0f) ? sj : 0.2f * sj;
        ej[p] = (j8 < 6) ? __expf(sj) * mv[p] : 0.0f;
    }

    // ---- pooling with RAW e-weights; Se accumulated from same broadcasts ----
    float4 acc[2];
    float  Se[2];
    #pragma unroll
    for (int p = 0; p < 2; ++p) {
        const float an = (h == 0) ? e0[p] : 0.0f;    // node slot counted once
        acc[p].x = an * nv[p].x;
        acc[p].y = an * nv[p].y;
        acc[p].z = an * nv[p].z;
        acc[p].w = an * nv[p].w;
        Se[p] = 0.0f;
    }
    #pragma unroll
    for (int i = 0; i < 6; ++i) {
        #pragma unroll
        for (int p = 0; p < 2; ++p) {
            const float bi = __shfl(ej[p], i, 8);    // e of slot 1+2i+h
            acc[p].x += bi * x[p][i].x;
            acc[p].y += bi * x[p][i].y;
            acc[p].z += bi * x[p][i].z;
            acc[p].w += bi * x[p][i].w;
            Se[p]    += bi;
        }
    }
    // cross-half combine (acc and Se), then normalize once
    #pragma unroll
    for (int p = 0; p < 2; ++p) {
        acc[p].x += __shfl_xor(acc[p].x, 32, 64);
        acc[p].y += __shfl_xor(acc[p].y, 32, 64);
        acc[p].z += __shfl_xor(acc[p].z, 32, 64);
        acc[p].w += __shfl_xor(acc[p].w, 32, 64);
        Se[p]    += __shfl_xor(Se[p],    32, 64);
    }
    #pragma unroll
    for (int p = 0; p < 2; ++p) {
        const float S   = e0[p] + Se[p];
        const float inv = 1.0f / (S + 1e-16f);
        if (h == 0) {
            const int lrow = wave * 2 + p;
            float4 o;
            o.x = acc[p].x * inv;
            o.y = acc[p].y * inv;
            o.z = acc[p].z * inv;
            o.w = acc[p].w * inv;
            *(float4*)(hb + lrow * HB_STRIDE + 4 * li) = o;
            if (li == 0) scL[lrow] = S * inv;        // sum of attn weights
        }
    }
    __syncthreads();

    // ---- Phase B: out[8x128] = hb @ Wv + bv * scale ----
    const int rg = t >> 5;                        // row 0..7
    const int cg = t & 31;                        // cols 4cg..4cg+3
    const float4* wv4 = (const float4*)Wv;        // [k][32] of float4
    const float* hrow = hb + rg * HB_STRIDE;

    float4 vacc = make_float4(0.0f, 0.0f, 0.0f, 0.0f);
    #pragma unroll 16
    for (int k = 0; k < D_; ++k) {
        const float a  = hrow[k];                 // 2 addrs/wave: broadcast
        const float4 w = wv4[k * 32 + cg];
        vacc.x += a * w.x;
        vacc.y += a * w.y;
        vacc.z += a * w.z;
        vacc.w += a * w.w;
    }

    const float4 bvv = ((const float4*)bv)[cg];
    const float  s   = scL[rg];
    float4 o;
    o.x = vacc.x + bvv.x * s;
    o.y = vacc.y + bvv.y * s;
    o.z = vacc.z + bvv.z * s;
    o.w = vacc.w + bvv.w * s;
    *(float4*)(out + (size_t)(blockIdx.x * ROWS + rg) * D_ + cg * 4) = o;
}

// ---------------------------------------------------------------------------
extern "C" void kernel_launch(void* const* d_in, const int* in_sizes, int n_in,
                              void* d_out, int out_size, void* d_ws, size_t ws_size,
                              hipStream_t stream) {
    const float* nodes = (const float*)d_in[0];
    const float* neigh = (const float*)d_in[1];
    const float* mask  = (const float*)d_in[2];
    const float* Wq    = (const float*)d_in[3];
    const float* bq    = (const float*)d_in[4];
    const float* Wk    = (const float*)d_in[5];
    const float* bk    = (const float*)d_in[6];
    const float* Wv    = (const float*)d_in[7];
    const float* bv    = (const float*)d_in[8];
    const float* wa_q  = (const float*)d_in[9];
    const float* wa_k  = (const float*)d_in[10];
    const float* ba    = (const float*)d_in[11];
    float* out = (float*)d_out;
    float* ws  = (float*)d_ws;

    prep_kernel<<<258, 64, 0, stream>>>(Wq, bq, Wk, bk, wa_q, wa_k, ws);
    fused_kernel<<<BN / ROWS, 256, 0, stream>>>(nodes, neigh, mask, ba, ws, Wv, bv, out);
}

// Round 4
// 188.821 us; speedup vs baseline: 1.0645x; 1.0545x over previous
//
#include <hip/hip_runtime.h>

// GAT: B=256, N=64, K=12, D=128
// Algebra: wq_eff = Wq @ wa_q, wk_eff = Wk @ wa_k; V-projection commutes
// with the attention average: out = h_bar @ Wv + bv * (sum attn).
//
// R4 (resubmit; previous round hit a GPU-acquisition timeout, never ran):
// defeat the compiler's register-thrifty serialization (R3 post-mortem:
// VGPR=48 proves prefetched x[] was re-loaded from memory, pipeline erased):
//  - depth-4 software pipeline: wave owns 4 pairs (ROWS=16, grid 1024);
//    issue pair i+1's loads, sched_barrier(0), compute pair i. Loads stay
//    in flight across the compute (counted-vmcnt pattern).
//  - asm "+v" liveness pins on x/nv/mv AFTER the dot products (no extra
//    waitcnt) so the compiler cannot re-load them for pooling.
//  - __launch_bounds__(256,4): VGPR cap 128 (~105 needed), 4 waves/SIMD
//    matches the 4 blocks/CU grid.
//  - Phase B: ds_read_b128 row quads (64 DS instr/wave vs 256), 2 rows per
//    thread, Wv float4 stream amortized over both rows.

#define B_  256
#define N_  64
#define K_  12
#define D_  128
#define BN  (B_ * N_)          // 16384 (b,n) pairs
#define ROWS 16                // pairs per block; wave owns 4
#define HB_STRIDE 132          // 528B rows: 16B-aligned, bank-offset 4/row

#define PIN4(v)  asm volatile("" : "+v"(v.x), "+v"(v.y), "+v"(v.z), "+v"(v.w))
#define PIN1(s)  asm volatile("" : "+v"(s))

// ws float layout: [0..127] wq_eff | [128..255] wk_eff | [256] cq | [257] ckb
// ---------------------------------------------------------------------------
__global__ void prep_kernel(const float* __restrict__ Wq, const float* __restrict__ bq,
                            const float* __restrict__ Wk, const float* __restrict__ bk,
                            const float* __restrict__ wa_q, const float* __restrict__ wa_k,
                            float* __restrict__ ws) {
    int g = blockIdx.x;
    int l = threadIdx.x;            // 0..63, lane owns elements 2l, 2l+1
    const float* row;
    const float* wa;
    float* outp;
    if (g < 128)      { row = Wq + g * D_;         wa = wa_q; outp = ws + g; }
    else if (g < 256) { row = Wk + (g - 128) * D_; wa = wa_k; outp = ws + 128 + (g - 128); }
    else if (g == 256){ row = bq;                  wa = wa_q; outp = ws + 256; }
    else              { row = bk;                  wa = wa_k; outp = ws + 257; }

    float2 r = ((const float2*)row)[l];
    float2 w = ((const float2*)wa)[l];
    float p = r.x * w.x + r.y * w.y;
    #pragma unroll
    for (int m = 1; m < 64; m <<= 1) p += __shfl_xor(p, m, 64);
    if (l == 0) *outp = p;
}

// ---------------------------------------------------------------------------
// grid = BN/16 = 1024 blocks x 256 threads. Block owns 16 pairs; wave owns 4.
// Lane l: half h=l>>5 covers neighbor slots {1+2i+h}; li=l&31 owns features
// 4li..4li+3. After 3 RS + 2 finish stages lane (l&7) holds one full dot.
__global__ void __launch_bounds__(256, 4)
fused_kernel(const float* __restrict__ nodes, const float* __restrict__ neigh,
             const float* __restrict__ mask, const float* __restrict__ ba_p,
             const float* __restrict__ ws, const float* __restrict__ Wv,
             const float* __restrict__ bv, float* __restrict__ out) {
    __shared__ float hb[ROWS * HB_STRIDE];
    __shared__ float scL[ROWS];

    const int t    = threadIdx.x;
    const int wave = t >> 6;
    const int l    = t & 63;
    const int li   = l & 31;
    const int h    = l >> 5;
    const int j8   = l & 7;

    const float cq  = ws[256];
    const float ckb = ws[257];
    const float ba  = ba_p[0];
    const float cst = cq + ckb + ba;
    const float4 wqe4 = ((const float4*)ws)[li];          // wq_eff[4li..]
    const float4 wke4 = ((const float4*)(ws + 128))[li];  // wk_eff[4li..]

    const int idx0 = blockIdx.x * ROWS + wave * 4;

    float4 xb[2][6];
    float4 nv[2];
    float  mv[2];

    #define LOADP(buf, pi) do {                                              \
        const int idx_ = idx0 + (pi);                                        \
        nv[buf] = ((const float4*)(nodes + (size_t)idx_ * D_))[li];          \
        const float4* gp_ = (const float4*)(neigh + (size_t)idx_ * (K_*D_)); \
        xb[buf][0] = gp_[0 * 64 + l];                                        \
        xb[buf][1] = gp_[1 * 64 + l];                                        \
        xb[buf][2] = gp_[2 * 64 + l];                                        \
        xb[buf][3] = gp_[3 * 64 + l];                                        \
        xb[buf][4] = gp_[4 * 64 + l];                                        \
        xb[buf][5] = gp_[5 * 64 + l];                                        \
        mv[buf] = (j8 < 6) ? mask[(size_t)idx_ * K_ + 2 * j8 + h] : 0.0f;    \
    } while (0)

    LOADP(0, 0);                                  // prologue

    #pragma unroll
    for (int i = 0; i < 4; ++i) {
        const int b  = i & 1;
        const int nb = b ^ 1;
        if (i < 3) LOADP(nb, i + 1);              // prefetch next pair
        __builtin_amdgcn_sched_barrier(0);        // pin: loads stay above

        // ---- per-lane partial dots (8 values) ----
        float v[8];
        v[7] = nv[b].x*wqe4.x + nv[b].y*wqe4.y + nv[b].z*wqe4.z + nv[b].w*wqe4.w;
        v[6] = nv[b].x*wke4.x + nv[b].y*wke4.y + nv[b].z*wke4.z + nv[b].w*wke4.w;
        #pragma unroll
        for (int q = 0; q < 6; ++q)
            v[q] = xb[b][q].x*wke4.x + xb[b][q].y*wke4.y
                 + xb[b][q].z*wke4.z + xb[b][q].w*wke4.w;

        // pin x/nv/mv: values already available (dots consumed them), but
        // now the compiler cannot re-load them from memory for the pooling.
        PIN4(xb[b][0]); PIN4(xb[b][1]); PIN4(xb[b][2]);
        PIN4(xb[b][3]); PIN4(xb[b][4]); PIN4(xb[b][5]);
        PIN4(nv[b]);    PIN1(mv[b]);

        // ---- reduce-scatter: 3 RS stages + 2 finish ----
        float A0, A1, A2, A3;
        {
            const bool hi = (l & 1);
            float g0 = hi ? v[0] : v[1];
            float g1 = hi ? v[2] : v[3];
            float g2 = hi ? v[4] : v[5];
            float g3 = hi ? v[6] : v[7];
            g0 = __shfl_xor(g0, 1, 64);
            g1 = __shfl_xor(g1, 1, 64);
            g2 = __shfl_xor(g2, 1, 64);
            g3 = __shfl_xor(g3, 1, 64);
            A0 = (hi ? v[1] : v[0]) + g0;
            A1 = (hi ? v[3] : v[2]) + g1;
            A2 = (hi ? v[5] : v[4]) + g2;
            A3 = (hi ? v[7] : v[6]) + g3;
        }
        float B0, B1;
        {
            const bool hi = (l & 2);
            float g0 = hi ? A0 : A1;
            float g1 = hi ? A2 : A3;
            g0 = __shfl_xor(g0, 2, 64);
            g1 = __shfl_xor(g1, 2, 64);
            B0 = (hi ? A1 : A0) + g0;
            B1 = (hi ? A3 : A2) + g1;
        }
        float c;
        {
            const bool hi = (l & 4);
            float g = hi ? B0 : B1;
            g = __shfl_xor(g, 4, 64);
            c = (hi ? B1 : B0) + g;
        }
        c += __shfl_xor(c, 8, 64);
        c += __shfl_xor(c, 16, 64);
        // c = full dot of value j8: j8<6 -> slot 1+2*j8+h; 6 -> node-k; 7 -> q

        const float pq  = __shfl(c, 7, 8);        // replicated per 8-group
        const float pkn = __shfl(c, 6, 8);
        const float base = pq + cst;

        float s0 = base + pkn;
        s0 = (s0 >= 0.0f) ? s0 : 0.2f * s0;       // LeakyReLU(0.2)
        const float e0 = __expf(s0);
        float sj = base + c;
        sj = (sj >= 0.0f) ? sj : 0.2f * sj;
        const float ej = (j8 < 6) ? __expf(sj) * mv[b] : 0.0f;

        // ---- pooling with raw e-weights; Se from the same broadcasts ----
        const float an = (h == 0) ? e0 : 0.0f;    // node slot counted once
        float4 acc;
        acc.x = an * nv[b].x;
        acc.y = an * nv[b].y;
        acc.z = an * nv[b].z;
        acc.w = an * nv[b].w;
        float Se = 0.0f;
        #pragma unroll
        for (int q = 0; q < 6; ++q) {
            const float bi = __shfl(ej, q, 8);    // e of slot 1+2q+h
            acc.x += bi * xb[b][q].x;
            acc.y += bi * xb[b][q].y;
            acc.z += bi * xb[b][q].z;
            acc.w += bi * xb[b][q].w;
            Se    += bi;
        }
        acc.x += __shfl_xor(acc.x, 32, 64);       // cross-half combine
        acc.y += __shfl_xor(acc.y, 32, 64);
        acc.z += __shfl_xor(acc.z, 32, 64);
        acc.w += __shfl_xor(acc.w, 32, 64);
        Se    += __shfl_xor(Se,    32, 64);

        const float S   = e0 + Se;
        const float inv = 1.0f / (S + 1e-16f);
        if (h == 0) {
            const int lrow = wave * 4 + i;
            float4 o;
            o.x = acc.x * inv;
            o.y = acc.y * inv;
            o.z = acc.z * inv;
            o.w = acc.w * inv;
            *(float4*)(hb + lrow * HB_STRIDE + 4 * li) = o;
            if (li == 0) scL[lrow] = S * inv;     // sum of attn weights
        }
    }
    #undef LOADP
    __syncthreads();

    // ---- Phase B: out[16x128] = hb @ Wv + bv * scale ----
    // thread (rg=t>>5, cg=t&31) does rows {rg, rg+8}, cols 4cg..4cg+3.
    // hb read as b128 row-quads: 2 distinct addrs per instr (broadcast).
    const int rg = t >> 5;                        // 0..7
    const int cg = t & 31;
    const float4* wv4 = (const float4*)Wv;        // [k][32] of float4
    const float* hr0 = hb + rg * HB_STRIDE;
    const float* hr1 = hb + (rg + 8) * HB_STRIDE;

    float4 acc0 = make_float4(0.0f, 0.0f, 0.0f, 0.0f);
    float4 acc1 = make_float4(0.0f, 0.0f, 0.0f, 0.0f);
    #pragma unroll 8
    for (int kq = 0; kq < 32; ++kq) {
        const float4 a0 = *(const float4*)(hr0 + 4 * kq);
        const float4 a1 = *(const float4*)(hr1 + 4 * kq);
        #pragma unroll
        for (int e = 0; e < 4; ++e) {
            const float4 w = wv4[(4 * kq + e) * 32 + cg];
            const float f0 = (e == 0) ? a0.x : (e == 1) ? a0.y : (e == 2) ? a0.z : a0.w;
            const float f1 = (e == 0) ? a1.x : (e == 1) ? a1.y : (e == 2) ? a1.z : a1.w;
            acc0.x += f0 * w.x; acc0.y += f0 * w.y;
            acc0.z += f0 * w.z; acc0.w += f0 * w.w;
            acc1.x += f1 * w.x; acc1.y += f1 * w.y;
            acc1.z += f1 * w.z; acc1.w += f1 * w.w;
        }
    }

    const float4 bvv = ((const float4*)bv)[cg];
    const int row0 = blockIdx.x * ROWS;
    {
        const float s = scL[rg];
        float4 o;
        o.x = acc0.x + bvv.x * s;
        o.y = acc0.y + bvv.y * s;
        o.z = acc0.z + bvv.z * s;
        o.w = acc0.w + bvv.w * s;
        *(float4*)(out + (size_t)(row0 + rg) * D_ + cg * 4) = o;
    }
    {
        const float s = scL[rg + 8];
        float4 o;
        o.x = acc1.x + bvv.x * s;
        o.y = acc1.y + bvv.y * s;
        o.z = acc1.z + bvv.z * s;
        o.w = acc1.w + bvv.w * s;
        *(float4*)(out + (size_t)(row0 + rg + 8) * D_ + cg * 4) = o;
    }
}

// ---------------------------------------------------------------------------
extern "C" void kernel_launch(void* const* d_in, const int* in_sizes, int n_in,
                              void* d_out, int out_size, void* d_ws, size_t ws_size,
                              hipStream_t stream) {
    const float* nodes = (const float*)d_in[0];
    const float* neigh = (const float*)d_in[1];
    const float* mask  = (const float*)d_in[2];
    const float* Wq    = (const float*)d_in[3];
    const float* bq    = (const float*)d_in[4];
    const float* Wk    = (const float*)d_in[5];
    const float* bk    = (const float*)d_in[6];
    const float* Wv    = (const float*)d_in[7];
    const float* bv    = (const float*)d_in[8];
    const float* wa_q  = (const float*)d_in[9];
    const float* wa_k  = (const float*)d_in[10];
    const float* ba    = (const float*)d_in[11];
    float* out = (float*)d_out;
    float* ws  = (float*)d_ws;

    prep_kernel<<<258, 64, 0, stream>>>(Wq, bq, Wk, bk, wa_q, wa_k, ws);
    fused_kernel<<<BN / ROWS, 256, 0, stream>>>(nodes, neigh, mask, ba, ws, Wv, bv, out);
}